// Round 18
// baseline (424.568 us; speedup 1.0000x reference)
//
#include <hip/hip_runtime.h>

typedef _Float16 f16;
typedef _Float16 f16x2 __attribute__((ext_vector_type(2)));
typedef _Float16 f16x4 __attribute__((ext_vector_type(4)));
typedef _Float16 f16x8 __attribute__((ext_vector_type(8)));
typedef float f32x4 __attribute__((ext_vector_type(4)));

#define NT 64
#define CH 192
#define NH 6
#define MH 256
#define BWIN 4096
#define LOG2E 1.44269504f

#define STOK 200            // tok/ao row stride (f16): 400 B
#define SMEM_FUSED 49152

#define MFMA16(a, b, c) __builtin_amdgcn_mfma_f32_16x16x16f16(a, b, c, 0, 0, 0)
#define MFMA32(a, b, c) __builtin_amdgcn_mfma_f32_16x16x32_f16(a, b, c, 0, 0, 0)

// swizzled index into a [64][32] f16 qk tile (fused fallback only)
__device__ __forceinline__ int qkidx(int n, int d) {
    return n * 32 + ((((d >> 3) + (n >> 1)) & 3) << 3) + (d & 7);
}

// ---------------- bias table ----------------
__global__ void bias_kernel(const float* __restrict__ mW1, const float* __restrict__ mb1,
                            const float* __restrict__ mW2, const float* __restrict__ mb2,
                            float* __restrict__ bias_tbl) {
    int p = blockIdx.x * blockDim.x + threadIdx.x;
    if (p >= NT * NT) return;
    int n = p >> 6, m = p & 63;
    float di = (float)((n >> 3) - (m >> 3));
    float dj = (float)((n & 7) - (m & 7));
    float r0 = copysignf(log1pf(fabsf(di)), di);
    float r1 = copysignf(log1pf(fabsf(dj)), dj);
    float acc[NH];
#pragma unroll
    for (int h = 0; h < NH; h++) acc[h] = mb2[h];
    for (int k = 0; k < MH; k++) {
        float hv = fmaxf(r0 * mW1[k] + r1 * mW1[MH + k] + mb1[k], 0.0f);
#pragma unroll
        for (int h = 0; h < NH; h++) acc[h] += hv * mW2[k * NH + h];
    }
#pragma unroll
    for (int h = 0; h < NH; h++) bias_tbl[h * (NT * NT) + p] = acc[h];
}

// ---------------- fragment-packed weight prep ----------------
__global__ void prep_kernel(const float* __restrict__ Wqkv, const float* __restrict__ Wproj,
                            f16* __restrict__ Wpk, f16* __restrict__ Wpp) {
    int i = blockIdx.x * blockDim.x + threadIdx.x;
    const int NQ = 36 * 6 * 64 * 8;
    if (i < NQ) {
        int t = i & 7, lane = (i >> 3) & 63, ks = (i >> 9) % 6, ct = i >> 9; ct /= 6;
        int o = 16 * ct + (lane & 15);
        int c = ks * 32 + (lane >> 4) * 8 + t;
        Wpk[i] = (f16)Wqkv[c * 576 + o];
    } else if (i < NQ + 12 * 6 * 64 * 8) {
        int j = i - NQ;
        int t = j & 7, lane = (j >> 3) & 63, ks = (j >> 9) % 6, ct = j >> 9; ct /= 6;
        int o = 16 * ct + (lane & 15);
        int c = ks * 32 + (lane >> 4) * 8 + t;
        Wpp[j] = (f16)Wproj[c * 192 + o];
    }
}

// ---------------- combined (mask + bias) * log2e table ----------------
__global__ void comb_kernel(const float* __restrict__ mask, const float* __restrict__ bias_tbl,
                            float* __restrict__ comb) {
    int j = blockIdx.x * blockDim.x + threadIdx.x;
    if (j >= 64 * NH * NT * NT) return;
    int im = j / (NH * NT * NT);
    int rem = j % (NH * NT * NT);
    int h = rem >> 12;
    int p = rem & 4095;
    comb[j] = (mask[im * 4096 + p] + bias_tbl[h * 4096 + p]) * LOG2E;
}

// norm (over d=32) + plain [n][32] store, transposed accumulator layout
__device__ __forceinline__ void norm_store(const f32x4 (&acc)[2][4], const float* __restrict__ bq,
                                           int c16, int g4, f16* __restrict__ dst) {
    f32x4 bb0 = *(const f32x4*)(bq + 4 * g4);
    f32x4 bb1 = *(const f32x4*)(bq + 16 + 4 * g4);
#pragma unroll
    for (int nt = 0; nt < 4; nt++) {
        float a0[4], a1[4];
        float ss = 0.f;
#pragma unroll
        for (int r = 0; r < 4; r++) {
            a0[r] = acc[0][nt][r] + bb0[r];
            a1[r] = acc[1][nt][r] + bb1[r];
            ss += a0[r] * a0[r] + a1[r] * a1[r];
        }
        ss += __shfl_xor(ss, 16);
        ss += __shfl_xor(ss, 32);
        float inv = 1.0f / fmaxf(sqrtf(ss), 1e-12f);
        f16x4 h0, h1;
#pragma unroll
        for (int r = 0; r < 4; r++) {
            h0[r] = (f16)(a0[r] * inv);
            h1[r] = (f16)(a1[r] * inv);
        }
        *(f16x4*)(dst + (16 * nt + c16) * 32 + 4 * g4)      = h0;
        *(f16x4*)(dst + (16 * nt + c16) * 32 + 16 + 4 * g4) = h1;
    }
}

// =======================================================================
// SPLIT K1: qkv GEMM + norm -> ws. 1 block = 1 window, 6 waves, wave=head.
// Q and K passes FUSED (shared tok fragments); then V pass.
// ws per (b,head) 12KB: q [64][32], k [64][32], v f16x8 pair-packed.
// =======================================================================
__launch_bounds__(384, 1)
__global__ void qkv_kernel(const float* __restrict__ x, const float* __restrict__ bqkv,
                           const f16* __restrict__ Wpk, f16* __restrict__ qkv_ws) {
    __shared__ __align__(16) f16 tok[NT * STOK];

    const int tid = threadIdx.x;
    const int l   = tid & 63;
    const int w   = __builtin_amdgcn_readfirstlane(tid >> 6);
    const int b   = blockIdx.x;
    const int c16 = l & 15;
    const int g4  = l >> 4;

    // stage x[b] (fp32 [c][n]) -> tok f16 [n][c]
    {
        const float* xb = x + (size_t)b * (CH * NT);
        const int n4 = 4 * c16;
#pragma unroll
        for (int i = 0; i < 4; i++) {
            int c = 32 * w + 8 * g4 + 2 * i;
            f32x4 a0 = *(const f32x4*)(xb + c * NT + n4);
            f32x4 a1 = *(const f32x4*)(xb + (c + 1) * NT + n4);
#pragma unroll
            for (int j = 0; j < 4; j++) {
                f16x2 p;
                p[0] = (f16)a0[j];
                p[1] = (f16)a1[j];
                *(f16x2*)(tok + (n4 + j) * STOK + c) = p;
            }
        }
    }
    __syncthreads();

    f16* dstq = qkv_ws + (size_t)(b * NH + w) * 6144;
    f16* dstk = dstq + 2048;
    f16* dstv = dstq + 4096;

    // ---- fused pass Q+K (transposed D[d][n]; tok fragments shared) ----
    {
        f32x4 accQ[2][4] = {}, accK[2][4] = {};
#pragma unroll
        for (int ks = 0; ks < 6; ks++) {
            f16x8 af[4];
#pragma unroll
            for (int nt = 0; nt < 4; nt++)
                af[nt] = *(const f16x8*)(tok + (16 * nt + c16) * STOK + ks * 32 + 8 * g4);
#pragma unroll
            for (int dt = 0; dt < 2; dt++) {
                f16x8 wq = *(const f16x8*)(Wpk + (((size_t)(2 * w + dt) * 6 + ks) * 64 + l) * 8);
                f16x8 wk = *(const f16x8*)(Wpk + (((size_t)(12 + 2 * w + dt) * 6 + ks) * 64 + l) * 8);
#pragma unroll
                for (int nt = 0; nt < 4; nt++) {
                    accQ[dt][nt] = MFMA32(wq, af[nt], accQ[dt][nt]);
                    accK[dt][nt] = MFMA32(wk, af[nt], accK[dt][nt]);
                }
            }
        }
        norm_store(accQ, bqkv + 32 * w, c16, g4, dstq);
        norm_store(accK, bqkv + CH + 32 * w, c16, g4, dstk);
    }
    // ---- pass V (natural D[m][d]) -> f16x8 pair-packed store ----
    {
        f32x4 acc[2][4] = {};
#pragma unroll
        for (int ks = 0; ks < 6; ks++) {
            f16x8 af[4];
#pragma unroll
            for (int mt = 0; mt < 4; mt++)
                af[mt] = *(const f16x8*)(tok + (16 * mt + c16) * STOK + ks * 32 + 8 * g4);
#pragma unroll
            for (int dt = 0; dt < 2; dt++) {
                f16x8 wf = *(const f16x8*)(Wpk + (((size_t)(24 + 2 * w + dt) * 6 + ks) * 64 + l) * 8);
#pragma unroll
                for (int mt = 0; mt < 4; mt++)
                    acc[dt][mt] = MFMA32(af[mt], wf, acc[dt][mt]);
            }
        }
        f16x4 hv[2][4];
#pragma unroll
        for (int dt = 0; dt < 2; dt++) {
            float bb = bqkv[384 + 32 * w + 16 * dt + c16];
#pragma unroll
            for (int mt = 0; mt < 4; mt++)
#pragma unroll
                for (int r = 0; r < 4; r++) hv[dt][mt][r] = (f16)(acc[dt][mt][r] + bb);
        }
#pragma unroll
        for (int p = 0; p < 4; p++) {
            int dt = p >> 1, m0 = 2 * (p & 1);
            f16x8 v8;
#pragma unroll
            for (int r = 0; r < 4; r++) { v8[r] = hv[dt][m0][r]; v8[4 + r] = hv[dt][m0 + 1][r]; }
            *(f16x8*)(dstv + (p * 64 + l) * 8) = v8;
        }
    }
}

// =======================================================================
// SPLIT K23: attention + proj (r13's measured-best version).
// 1 block = 1 window, 6 waves, wave=head; hoisted vb/wpp/cc loads.
// =======================================================================
__launch_bounds__(384, 1)
__global__ void attn2_kernel(const float* __restrict__ tau, const f16* __restrict__ Wpp,
                             const float* __restrict__ bproj, const float* __restrict__ comb,
                             const f16* __restrict__ qkv_ws, float* __restrict__ out) {
    __shared__ __align__(16) f16 ao[NT * STOK];

    const int tid = threadIdx.x;
    const int l   = tid & 63;
    const int w   = __builtin_amdgcn_readfirstlane(tid >> 6);
    const int b   = blockIdx.x;
    const int c16 = l & 15;
    const int g4  = l >> 4;

    const f16* qg = qkv_ws + (size_t)(b * NH + w) * 6144;
    const f16* kg = qg + 2048;
    const f16* vg = qg + 4096;

    // hoist: V PV-B-frags (pair-packed 16B loads) + proj weight frags
    f16x4 vb[2][4];
#pragma unroll
    for (int p = 0; p < 4; p++) {
        f16x8 v8 = *(const f16x8*)(vg + (p * 64 + l) * 8);
        int dt = p >> 1, m0 = 2 * (p & 1);
#pragma unroll
        for (int r = 0; r < 4; r++) { vb[dt][m0][r] = v8[r]; vb[dt][m0 + 1][r] = v8[4 + r]; }
    }
    f16x8 wpp[6][2];
#pragma unroll
    for (int ks = 0; ks < 6; ks++)
#pragma unroll
        for (int c2 = 0; c2 < 2; c2++)
            wpp[ks][c2] = *(const f16x8*)(Wpp + (((size_t)(2 * w + c2) * 6 + ks) * 64 + l) * 8);

    const float itau_l2 = LOG2E / fmaxf(tau[w], 0.01f);
    const float* cb = comb + ((size_t)((b & 63) * NH + w)) * (NT * NT);

    // attention in two nt-halves (keeps S-tile at 32 regs)
#pragma unroll
    for (int half = 0; half < 2; half++) {
        // hoist: comb vectors for this half before the MFMA chain
        f32x4 cc[4][2];
#pragma unroll
        for (int mt = 0; mt < 4; mt++)
#pragma unroll
            for (int ntl = 0; ntl < 2; ntl++)
                cc[mt][ntl] = *(const f32x4*)(cb + (16 * (2 * half + ntl) + c16) * NT + 16 * mt + 4 * g4);

        f16x8 aqf[2];
#pragma unroll
        for (int ntl = 0; ntl < 2; ntl++)
            aqf[ntl] = *(const f16x8*)(qg + (16 * (2 * half + ntl) + c16) * 32 + 8 * g4);
        f16x8 akf[4];
#pragma unroll
        for (int mt = 0; mt < 4; mt++)
            akf[mt] = *(const f16x8*)(kg + (16 * mt + c16) * 32 + 8 * g4);

        f32x4 sv[4][2];   // [mt][ntl]
#pragma unroll
        for (int mt = 0; mt < 4; mt++)
#pragma unroll
            for (int ntl = 0; ntl < 2; ntl++) {
                f32x4 z = {};
                sv[mt][ntl] = MFMA32(akf[mt], aqf[ntl], z);
            }
        // epilogue: scale + comb
#pragma unroll
        for (int mt = 0; mt < 4; mt++)
#pragma unroll
            for (int ntl = 0; ntl < 2; ntl++)
#pragma unroll
                for (int r = 0; r < 4; r++)
                    sv[mt][ntl][r] = sv[mt][ntl][r] * itau_l2 + cc[mt][ntl][r];
        // softmax over m, fold 1/sum
#pragma unroll
        for (int ntl = 0; ntl < 2; ntl++) {
            float mx = sv[0][ntl][0];
#pragma unroll
            for (int mt = 0; mt < 4; mt++)
#pragma unroll
                for (int r = 0; r < 4; r++) mx = fmaxf(mx, sv[mt][ntl][r]);
            mx = fmaxf(mx, __shfl_xor(mx, 16));
            mx = fmaxf(mx, __shfl_xor(mx, 32));
            float sum = 0.f;
#pragma unroll
            for (int mt = 0; mt < 4; mt++)
#pragma unroll
                for (int r = 0; r < 4; r++) {
                    float p = exp2f(sv[mt][ntl][r] - mx);
                    sv[mt][ntl][r] = p;
                    sum += p;
                }
            sum += __shfl_xor(sum, 16);
            sum += __shfl_xor(sum, 32);
            float ris = 1.0f / sum;
#pragma unroll
            for (int mt = 0; mt < 4; mt++)
#pragma unroll
                for (int r = 0; r < 4; r++) sv[mt][ntl][r] *= ris;
        }
        // P frags + PV
        f16x4 pa[4][2];
#pragma unroll
        for (int mk = 0; mk < 4; mk++)
#pragma unroll
            for (int ntl = 0; ntl < 2; ntl++) {
                f16x4 h;
#pragma unroll
                for (int r = 0; r < 4; r++) h[r] = (f16)sv[mk][ntl][r];
                pa[mk][ntl] = h;
            }
        f32x4 av[2][2] = {};
#pragma unroll
        for (int mk = 0; mk < 4; mk++)
#pragma unroll
            for (int ntl = 0; ntl < 2; ntl++)
#pragma unroll
                for (int dt = 0; dt < 2; dt++)
                    av[ntl][dt] = MFMA16(pa[mk][ntl], vb[dt][mk], av[ntl][dt]);
        // write ao LDS rows
#pragma unroll
        for (int ntl = 0; ntl < 2; ntl++)
#pragma unroll
            for (int dt = 0; dt < 2; dt++)
#pragma unroll
                for (int r = 0; r < 4; r++)
                    ao[(16 * (2 * half + ntl) + 4 * g4 + r) * STOK + 32 * w + 16 * dt + c16] =
                        (f16)av[ntl][dt][r];
    }
    __syncthreads();

    // proj GEMM (weights already in registers)
    f32x4 acc2[2][4] = {};
#pragma unroll
    for (int ks = 0; ks < 6; ks++) {
        f16x8 af[4];
#pragma unroll
        for (int rt = 0; rt < 4; rt++)
            af[rt] = *(const f16x8*)(ao + (16 * rt + c16) * STOK + ks * 32 + 8 * g4);
#pragma unroll
        for (int c2 = 0; c2 < 2; c2++)
#pragma unroll
            for (int rt = 0; rt < 4; rt++)
                acc2[c2][rt] = MFMA32(af[rt], wpp[ks][c2], acc2[c2][rt]);
    }
    float* ob = out + (size_t)b * (CH * NT);
#pragma unroll
    for (int c2 = 0; c2 < 2; c2++) {
        int c = 16 * (2 * w + c2) + c16;
        float bp = bproj[c];
#pragma unroll
        for (int rt = 0; rt < 4; rt++) {
            f32x4 o4 = acc2[c2][rt];
            o4[0] += bp; o4[1] += bp; o4[2] += bp; o4[3] += bp;
            *(f32x4*)(ob + c * NT + 16 * rt + 4 * g4) = o4;
        }
    }
}

// =======================================================================
// FUSED FALLBACK (r6 kernel, proven) — used when ws is too small
// =======================================================================
__launch_bounds__(384)
__global__ void attn_fused_kernel(const float* __restrict__ x, const float* __restrict__ bqkv,
                                  const float* __restrict__ bproj, const float* __restrict__ tau,
                                  const f16* __restrict__ Wpk, const f16* __restrict__ Wpp,
                                  const float* __restrict__ comb, float* __restrict__ out) {
    __shared__ __align__(16) char smem[SMEM_FUSED];
    f16* tok = (f16*)smem;
    f16* qk  = (f16*)smem;
    f16* ao  = (f16*)smem;

    const int b   = blockIdx.x;
    const int tid = threadIdx.x;
    const int l   = tid & 63;
    const int w   = __builtin_amdgcn_readfirstlane(tid >> 6);
    const int c16 = l & 15;
    const int g4  = l >> 4;

    {
        const float* xb = x + (size_t)b * (CH * NT);
        const int n4 = 4 * c16;
#pragma unroll
        for (int i = 0; i < 4; i++) {
            int c = 32 * w + 8 * g4 + 2 * i;
            f32x4 a0 = *(const f32x4*)(xb + c * NT + n4);
            f32x4 a1 = *(const f32x4*)(xb + (c + 1) * NT + n4);
#pragma unroll
            for (int j = 0; j < 4; j++) {
                f16x2 p;
                p[0] = (f16)a0[j];
                p[1] = (f16)a1[j];
                *(f16x2*)(tok + (n4 + j) * STOK + c) = p;
            }
        }
    }
    __syncthreads();

    f16x4 hq[2][4], hk[2][4];
    {
        f32x4 aq_[2][4] = {};
#pragma unroll
        for (int ks = 0; ks < 6; ks++) {
            f16x8 af[4];
#pragma unroll
            for (int nt = 0; nt < 4; nt++)
                af[nt] = *(const f16x8*)(tok + (16 * nt + c16) * STOK + ks * 32 + 8 * g4);
#pragma unroll
            for (int dt = 0; dt < 2; dt++) {
                f16x8 wf = *(const f16x8*)(Wpk + (((size_t)(2 * w + dt) * 6 + ks) * 64 + l) * 8);
#pragma unroll
                for (int nt = 0; nt < 4; nt++)
                    aq_[dt][nt] = MFMA32(wf, af[nt], aq_[dt][nt]);
            }
        }
#pragma unroll
        for (int dt = 0; dt < 2; dt++) {
            f32x4 bb = *(const f32x4*)(bqkv + 32 * w + 16 * dt + 4 * g4);
#pragma unroll
            for (int nt = 0; nt < 4; nt++)
#pragma unroll
                for (int r = 0; r < 4; r++) aq_[dt][nt][r] += bb[r];
        }
#pragma unroll
        for (int nt = 0; nt < 4; nt++) {
            float ss = 0.f;
#pragma unroll
            for (int dt = 0; dt < 2; dt++)
#pragma unroll
                for (int r = 0; r < 4; r++) ss += aq_[dt][nt][r] * aq_[dt][nt][r];
            ss += __shfl_xor(ss, 16);
            ss += __shfl_xor(ss, 32);
            float iq = 1.0f / fmaxf(sqrtf(ss), 1e-12f);
#pragma unroll
            for (int dt = 0; dt < 2; dt++)
#pragma unroll
                for (int r = 0; r < 4; r++) hq[dt][nt][r] = (f16)(aq_[dt][nt][r] * iq);
        }
    }
    {
        f32x4 ak_[2][4] = {};
#pragma unroll
        for (int ks = 0; ks < 6; ks++) {
            f16x8 af[4];
#pragma unroll
            for (int nt = 0; nt < 4; nt++)
                af[nt] = *(const f16x8*)(tok + (16 * nt + c16) * STOK + ks * 32 + 8 * g4);
#pragma unroll
            for (int dt = 0; dt < 2; dt++) {
                f16x8 wf = *(const f16x8*)(Wpk + (((size_t)(12 + 2 * w + dt) * 6 + ks) * 64 + l) * 8);
#pragma unroll
                for (int nt = 0; nt < 4; nt++)
                    ak_[dt][nt] = MFMA32(wf, af[nt], ak_[dt][nt]);
            }
        }
#pragma unroll
        for (int dt = 0; dt < 2; dt++) {
            f32x4 bb = *(const f32x4*)(bqkv + 192 + 32 * w + 16 * dt + 4 * g4);
#pragma unroll
            for (int nt = 0; nt < 4; nt++)
#pragma unroll
                for (int r = 0; r < 4; r++) ak_[dt][nt][r] += bb[r];
        }
#pragma unroll
        for (int nt = 0; nt < 4; nt++) {
            float ss = 0.f;
#pragma unroll
            for (int dt = 0; dt < 2; dt++)
#pragma unroll
                for (int r = 0; r < 4; r++) ss += ak_[dt][nt][r] * ak_[dt][nt][r];
            ss += __shfl_xor(ss, 16);
            ss += __shfl_xor(ss, 32);
            float ik = 1.0f / fmaxf(sqrtf(ss), 1e-12f);
#pragma unroll
            for (int dt = 0; dt < 2; dt++)
#pragma unroll
                for (int r = 0; r < 4; r++) hk[dt][nt][r] = (f16)(ak_[dt][nt][r] * ik);
        }
    }
    f16x4 vb[2][4];
    {
        f32x4 av_[2][4] = {};
#pragma unroll
        for (int ks = 0; ks < 6; ks++) {
            f16x8 af[4];
#pragma unroll
            for (int mt = 0; mt < 4; mt++)
                af[mt] = *(const f16x8*)(tok + (16 * mt + c16) * STOK + ks * 32 + 8 * g4);
#pragma unroll
            for (int dt = 0; dt < 2; dt++) {
                f16x8 wf = *(const f16x8*)(Wpk + (((size_t)(24 + 2 * w + dt) * 6 + ks) * 64 + l) * 8);
#pragma unroll
                for (int mt = 0; mt < 4; mt++)
                    av_[dt][mt] = MFMA32(af[mt], wf, av_[dt][mt]);
            }
        }
#pragma unroll
        for (int dt = 0; dt < 2; dt++) {
            float bb = bqkv[384 + 32 * w + 16 * dt + c16];
#pragma unroll
            for (int mt = 0; mt < 4; mt++)
#pragma unroll
                for (int r = 0; r < 4; r++) vb[dt][mt][r] = (f16)(av_[dt][mt][r] + bb);
        }
    }
    __syncthreads();

    f16* qh = qk + (w * 2 + 0) * 2048;
    f16* kh = qk + (w * 2 + 1) * 2048;
#pragma unroll
    for (int nt = 0; nt < 4; nt++)
#pragma unroll
        for (int dt = 0; dt < 2; dt++) {
            int base = qkidx(16 * nt + c16, 16 * dt + 4 * g4);
            *(f16x2*)(qh + base)     = f16x2{hq[dt][nt][0], hq[dt][nt][1]};
            *(f16x2*)(qh + base + 2) = f16x2{hq[dt][nt][2], hq[dt][nt][3]};
            *(f16x2*)(kh + base)     = f16x2{hk[dt][nt][0], hk[dt][nt][1]};
            *(f16x2*)(kh + base + 2) = f16x2{hk[dt][nt][2], hk[dt][nt][3]};
        }

    f32x4 sv[4][4];
    {
        f16x8 aqf[4];
#pragma unroll
        for (int t = 0; t < 4; t++)
            aqf[t] = *(const f16x8*)(qh + qkidx(16 * t + c16, 8 * g4));
#pragma unroll
        for (int mt = 0; mt < 4; mt++) {
            f16x8 akf = *(const f16x8*)(kh + qkidx(16 * mt + c16, 8 * g4));
#pragma unroll
            for (int nt = 0; nt < 4; nt++) {
                f32x4 z = {};
                sv[mt][nt] = MFMA32(akf, aqf[nt], z);
            }
        }
    }
    {
        const float itau_l2 = LOG2E / fmaxf(tau[w], 0.01f);
        const float* cb = comb + ((size_t)((b & 63) * NH + w)) * (NT * NT);
#pragma unroll
        for (int mt = 0; mt < 4; mt++)
#pragma unroll
            for (int nt = 0; nt < 4; nt++) {
                f32x4 cc = *(const f32x4*)(cb + (16 * nt + c16) * NT + 16 * mt + 4 * g4);
#pragma unroll
                for (int r = 0; r < 4; r++)
                    sv[mt][nt][r] = sv[mt][nt][r] * itau_l2 + cc[r];
            }
    }
#pragma unroll
    for (int nt = 0; nt < 4; nt++) {
        float mx = sv[0][nt][0];
#pragma unroll
        for (int mt = 0; mt < 4; mt++)
#pragma unroll
            for (int r = 0; r < 4; r++) mx = fmaxf(mx, sv[mt][nt][r]);
        mx = fmaxf(mx, __shfl_xor(mx, 16));
        mx = fmaxf(mx, __shfl_xor(mx, 32));
        float sum = 0.f;
#pragma unroll
        for (int mt = 0; mt < 4; mt++)
#pragma unroll
            for (int r = 0; r < 4; r++) {
                float p = exp2f(sv[mt][nt][r] - mx);
                sv[mt][nt][r] = p;
                sum += p;
            }
        sum += __shfl_xor(sum, 16);
        sum += __shfl_xor(sum, 32);
        float ris = 1.0f / sum;
#pragma unroll
        for (int mt = 0; mt < 4; mt++)
#pragma unroll
            for (int r = 0; r < 4; r++) sv[mt][nt][r] *= ris;
    }
    f16x4 pa[4][4];
#pragma unroll
    for (int mk = 0; mk < 4; mk++)
#pragma unroll
        for (int nt = 0; nt < 4; nt++) {
            f16x4 h;
#pragma unroll
            for (int r = 0; r < 4; r++) h[r] = (f16)sv[mk][nt][r];
            pa[mk][nt] = h;
        }
    f32x4 av[4][2] = {};
#pragma unroll
    for (int mk = 0; mk < 4; mk++)
#pragma unroll
        for (int nt = 0; nt < 4; nt++)
#pragma unroll
            for (int dt = 0; dt < 2; dt++)
                av[nt][dt] = MFMA16(pa[mk][nt], vb[dt][mk], av[nt][dt]);

    __syncthreads();
#pragma unroll
    for (int nt = 0; nt < 4; nt++)
#pragma unroll
        for (int dt = 0; dt < 2; dt++)
#pragma unroll
            for (int r = 0; r < 4; r++)
                ao[(16 * nt + 4 * g4 + r) * STOK + 32 * w + 16 * dt + c16] = (f16)av[nt][dt][r];
    __syncthreads();

    f32x4 acc2[2][4] = {};
#pragma unroll
    for (int ks = 0; ks < 6; ks++) {
        f16x8 af[4];
#pragma unroll
        for (int rt = 0; rt < 4; rt++)
            af[rt] = *(const f16x8*)(ao + (16 * rt + c16) * STOK + ks * 32 + 8 * g4);
#pragma unroll
        for (int c2 = 0; c2 < 2; c2++) {
            f16x8 bw = *(const f16x8*)(Wpp + (((size_t)(2 * w + c2) * 6 + ks) * 64 + l) * 8);
#pragma unroll
            for (int rt = 0; rt < 4; rt++)
                acc2[c2][rt] = MFMA32(af[rt], bw, acc2[c2][rt]);
        }
    }
    float* ob = out + (size_t)b * (CH * NT);
#pragma unroll
    for (int c2 = 0; c2 < 2; c2++) {
        int c = 16 * (2 * w + c2) + c16;
        float bp = bproj[c];
#pragma unroll
        for (int rt = 0; rt < 4; rt++) {
            f32x4 o4 = acc2[c2][rt];
            o4[0] += bp; o4[1] += bp; o4[2] += bp; o4[3] += bp;
            *(f32x4*)(ob + c * NT + 16 * rt + 4 * g4) = o4;
        }
    }
}

// ---------------- launcher ----------------
#define WS_BIAS 0
#define WS_WPK  98304
#define WS_WPP  319488
#define WS_COMB 393216
#define WS_QKV  6684672
#define WS_NEED ((size_t)WS_QKV + (size_t)BWIN * NH * 6144 * 2)

extern "C" void kernel_launch(void* const* d_in, const int* in_sizes, int n_in,
                              void* d_out, int out_size, void* d_ws, size_t ws_size,
                              hipStream_t stream) {
    const float* x     = (const float*)d_in[0];
    const float* mask  = (const float*)d_in[1];
    const float* Wqkv  = (const float*)d_in[2];
    const float* bqkv  = (const float*)d_in[3];
    const float* Wproj = (const float*)d_in[4];
    const float* bproj = (const float*)d_in[5];
    const float* mW1   = (const float*)d_in[6];
    const float* mb1   = (const float*)d_in[7];
    const float* mW2   = (const float*)d_in[8];
    const float* mb2   = (const float*)d_in[9];
    const float* tau   = (const float*)d_in[10];

    char* ws = (char*)d_ws;
    float* bias_tbl = (float*)(ws + WS_BIAS);
    f16*   Wpk      = (f16*)(ws + WS_WPK);
    f16*   Wpp      = (f16*)(ws + WS_WPP);
    float* comb     = (float*)(ws + WS_COMB);
    f16*   qkv_ws   = (f16*)(ws + WS_QKV);

    bias_kernel<<<16, 256, 0, stream>>>(mW1, mb1, mW2, mb2, bias_tbl);
    int prep_n = 36 * 6 * 64 * 8 + 12 * 6 * 64 * 8;
    prep_kernel<<<(prep_n + 255) / 256, 256, 0, stream>>>(Wqkv, Wproj, Wpk, Wpp);
    int comb_n = 64 * NH * NT * NT;
    comb_kernel<<<(comb_n + 255) / 256, 256, 0, stream>>>(mask, bias_tbl, comb);

    if (ws_size >= WS_NEED) {
        qkv_kernel<<<BWIN, 384, 0, stream>>>(x, bqkv, Wpk, qkv_ws);
        attn2_kernel<<<BWIN, 384, 0, stream>>>(tau, Wpp, bproj, comb, qkv_ws, (float*)d_out);
    } else {
        attn_fused_kernel<<<BWIN, 384, 0, stream>>>(x, bqkv, bproj, tau, Wpk, Wpp, comb,
                                                    (float*)d_out);
    }
}

// Round 19
// 313.874 us; speedup vs baseline: 1.3527x; 1.3527x over previous
//
#include <hip/hip_runtime.h>

typedef _Float16 f16;
typedef _Float16 f16x2 __attribute__((ext_vector_type(2)));
typedef _Float16 f16x4 __attribute__((ext_vector_type(4)));
typedef _Float16 f16x8 __attribute__((ext_vector_type(8)));
typedef float f32x4 __attribute__((ext_vector_type(4)));

#define NT 64
#define CH 192
#define NH 6
#define MH 256
#define BWIN 4096
#define LOG2E 1.44269504f

#define STOK 200            // tok/ao row stride (f16): 400 B
#define SMEM_FUSED 49152

#define MFMA16(a, b, c) __builtin_amdgcn_mfma_f32_16x16x16f16(a, b, c, 0, 0, 0)
#define MFMA32(a, b, c) __builtin_amdgcn_mfma_f32_16x16x32_f16(a, b, c, 0, 0, 0)

// swizzled index into a [64][32] f16 qk tile (fused fallback only)
__device__ __forceinline__ int qkidx(int n, int d) {
    return n * 32 + ((((d >> 3) + (n >> 1)) & 3) << 3) + (d & 7);
}

// ---------------- bias table ----------------
__global__ void bias_kernel(const float* __restrict__ mW1, const float* __restrict__ mb1,
                            const float* __restrict__ mW2, const float* __restrict__ mb2,
                            float* __restrict__ bias_tbl) {
    int p = blockIdx.x * blockDim.x + threadIdx.x;
    if (p >= NT * NT) return;
    int n = p >> 6, m = p & 63;
    float di = (float)((n >> 3) - (m >> 3));
    float dj = (float)((n & 7) - (m & 7));
    float r0 = copysignf(log1pf(fabsf(di)), di);
    float r1 = copysignf(log1pf(fabsf(dj)), dj);
    float acc[NH];
#pragma unroll
    for (int h = 0; h < NH; h++) acc[h] = mb2[h];
    for (int k = 0; k < MH; k++) {
        float hv = fmaxf(r0 * mW1[k] + r1 * mW1[MH + k] + mb1[k], 0.0f);
#pragma unroll
        for (int h = 0; h < NH; h++) acc[h] += hv * mW2[k * NH + h];
    }
#pragma unroll
    for (int h = 0; h < NH; h++) bias_tbl[h * (NT * NT) + p] = acc[h];
}

// ---------------- fragment-packed weight prep ----------------
__global__ void prep_kernel(const float* __restrict__ Wqkv, const float* __restrict__ Wproj,
                            f16* __restrict__ Wpk, f16* __restrict__ Wpp) {
    int i = blockIdx.x * blockDim.x + threadIdx.x;
    const int NQ = 36 * 6 * 64 * 8;
    if (i < NQ) {
        int t = i & 7, lane = (i >> 3) & 63, ks = (i >> 9) % 6, ct = i >> 9; ct /= 6;
        int o = 16 * ct + (lane & 15);
        int c = ks * 32 + (lane >> 4) * 8 + t;
        Wpk[i] = (f16)Wqkv[c * 576 + o];
    } else if (i < NQ + 12 * 6 * 64 * 8) {
        int j = i - NQ;
        int t = j & 7, lane = (j >> 3) & 63, ks = (j >> 9) % 6, ct = j >> 9; ct /= 6;
        int o = 16 * ct + (lane & 15);
        int c = ks * 32 + (lane >> 4) * 8 + t;
        Wpp[j] = (f16)Wproj[c * 192 + o];
    }
}

// ---------------- combined (mask + bias) * log2e table ----------------
__global__ void comb_kernel(const float* __restrict__ mask, const float* __restrict__ bias_tbl,
                            float* __restrict__ comb) {
    int j = blockIdx.x * blockDim.x + threadIdx.x;
    if (j >= 64 * NH * NT * NT) return;
    int im = j / (NH * NT * NT);
    int rem = j % (NH * NT * NT);
    int h = rem >> 12;
    int p = rem & 4095;
    comb[j] = (mask[im * 4096 + p] + bias_tbl[h * 4096 + p]) * LOG2E;
}

// =======================================================================
// SPLIT K1: qkv GEMM + norm -> ws. 1 block = 1 window, 6 waves, wave=head.
// waves_per_eu(1,2): scheduler register budget 256 -> hoisted loads stay.
// ws per (b,head) 12KB: q [64][32], k [64][32], v fragment-packed f16x4.
// =======================================================================
__attribute__((amdgpu_waves_per_eu(1, 2)))
__global__ void __launch_bounds__(384)
qkv_kernel(const float* __restrict__ x, const float* __restrict__ bqkv,
           const f16* __restrict__ Wpk, f16* __restrict__ qkv_ws) {
    __shared__ __align__(16) f16 tok[NT * STOK];

    const int tid = threadIdx.x;
    const int l   = tid & 63;
    const int w   = __builtin_amdgcn_readfirstlane(tid >> 6);
    const int b   = blockIdx.x;
    const int c16 = l & 15;
    const int g4  = l >> 4;

    // stage x[b] (fp32 [c][n]) -> tok f16 [n][c]
    {
        const float* xb = x + (size_t)b * (CH * NT);
        const int n4 = 4 * c16;
#pragma unroll
        for (int i = 0; i < 4; i++) {
            int c = 32 * w + 8 * g4 + 2 * i;
            f32x4 a0 = *(const f32x4*)(xb + c * NT + n4);
            f32x4 a1 = *(const f32x4*)(xb + (c + 1) * NT + n4);
#pragma unroll
            for (int j = 0; j < 4; j++) {
                f16x2 p;
                p[0] = (f16)a0[j];
                p[1] = (f16)a1[j];
                *(f16x2*)(tok + (n4 + j) * STOK + c) = p;
            }
        }
    }
    __syncthreads();

    f16* dstq = qkv_ws + (size_t)(b * NH + w) * 6144;
    f16* dstk = dstq + 2048;
    f16* dstv = dstq + 4096;

    // ---- pass Q (transposed D[d][n]); 12 weight frags hoisted ----
    {
        f16x8 wf[6][2];
#pragma unroll
        for (int ks = 0; ks < 6; ks++)
#pragma unroll
            for (int dt = 0; dt < 2; dt++)
                wf[ks][dt] = *(const f16x8*)(Wpk + (((size_t)(2 * w + dt) * 6 + ks) * 64 + l) * 8);
        f32x4 acc[2][4] = {};
#pragma unroll
        for (int ks = 0; ks < 6; ks++) {
            f16x8 af[4];
#pragma unroll
            for (int nt = 0; nt < 4; nt++)
                af[nt] = *(const f16x8*)(tok + (16 * nt + c16) * STOK + ks * 32 + 8 * g4);
#pragma unroll
            for (int dt = 0; dt < 2; dt++)
#pragma unroll
                for (int nt = 0; nt < 4; nt++)
                    acc[dt][nt] = MFMA32(wf[ks][dt], af[nt], acc[dt][nt]);
        }
        f32x4 bb0 = *(const f32x4*)(bqkv + 32 * w + 4 * g4);
        f32x4 bb1 = *(const f32x4*)(bqkv + 32 * w + 16 + 4 * g4);
#pragma unroll
        for (int nt = 0; nt < 4; nt++) {
            float a0[4], a1[4];
            float ss = 0.f;
#pragma unroll
            for (int r = 0; r < 4; r++) {
                a0[r] = acc[0][nt][r] + bb0[r];
                a1[r] = acc[1][nt][r] + bb1[r];
                ss += a0[r] * a0[r] + a1[r] * a1[r];
            }
            ss += __shfl_xor(ss, 16);
            ss += __shfl_xor(ss, 32);
            float inv = 1.0f / fmaxf(sqrtf(ss), 1e-12f);
            f16x4 h0, h1;
#pragma unroll
            for (int r = 0; r < 4; r++) {
                h0[r] = (f16)(a0[r] * inv);
                h1[r] = (f16)(a1[r] * inv);
            }
            *(f16x4*)(dstq + (16 * nt + c16) * 32 + 4 * g4)      = h0;
            *(f16x4*)(dstq + (16 * nt + c16) * 32 + 16 + 4 * g4) = h1;
        }
    }
    // ---- pass K ----
    {
        f16x8 wf[6][2];
#pragma unroll
        for (int ks = 0; ks < 6; ks++)
#pragma unroll
            for (int dt = 0; dt < 2; dt++)
                wf[ks][dt] = *(const f16x8*)(Wpk + (((size_t)(12 + 2 * w + dt) * 6 + ks) * 64 + l) * 8);
        f32x4 acc[2][4] = {};
#pragma unroll
        for (int ks = 0; ks < 6; ks++) {
            f16x8 af[4];
#pragma unroll
            for (int nt = 0; nt < 4; nt++)
                af[nt] = *(const f16x8*)(tok + (16 * nt + c16) * STOK + ks * 32 + 8 * g4);
#pragma unroll
            for (int dt = 0; dt < 2; dt++)
#pragma unroll
                for (int nt = 0; nt < 4; nt++)
                    acc[dt][nt] = MFMA32(wf[ks][dt], af[nt], acc[dt][nt]);
        }
        f32x4 bb0 = *(const f32x4*)(bqkv + CH + 32 * w + 4 * g4);
        f32x4 bb1 = *(const f32x4*)(bqkv + CH + 32 * w + 16 + 4 * g4);
#pragma unroll
        for (int nt = 0; nt < 4; nt++) {
            float a0[4], a1[4];
            float ss = 0.f;
#pragma unroll
            for (int r = 0; r < 4; r++) {
                a0[r] = acc[0][nt][r] + bb0[r];
                a1[r] = acc[1][nt][r] + bb1[r];
                ss += a0[r] * a0[r] + a1[r] * a1[r];
            }
            ss += __shfl_xor(ss, 16);
            ss += __shfl_xor(ss, 32);
            float inv = 1.0f / fmaxf(sqrtf(ss), 1e-12f);
            f16x4 h0, h1;
#pragma unroll
            for (int r = 0; r < 4; r++) {
                h0[r] = (f16)(a0[r] * inv);
                h1[r] = (f16)(a1[r] * inv);
            }
            *(f16x4*)(dstk + (16 * nt + c16) * 32 + 4 * g4)      = h0;
            *(f16x4*)(dstk + (16 * nt + c16) * 32 + 16 + 4 * g4) = h1;
        }
    }
    // ---- pass V (natural D[m][d]) -> fragment-packed store ----
    {
        f16x8 wf[6][2];
#pragma unroll
        for (int ks = 0; ks < 6; ks++)
#pragma unroll
            for (int dt = 0; dt < 2; dt++)
                wf[ks][dt] = *(const f16x8*)(Wpk + (((size_t)(24 + 2 * w + dt) * 6 + ks) * 64 + l) * 8);
        f32x4 acc[2][4] = {};
#pragma unroll
        for (int ks = 0; ks < 6; ks++) {
            f16x8 af[4];
#pragma unroll
            for (int mt = 0; mt < 4; mt++)
                af[mt] = *(const f16x8*)(tok + (16 * mt + c16) * STOK + ks * 32 + 8 * g4);
#pragma unroll
            for (int dt = 0; dt < 2; dt++)
#pragma unroll
                for (int mt = 0; mt < 4; mt++)
                    acc[dt][mt] = MFMA32(af[mt], wf[ks][dt], acc[dt][mt]);
        }
#pragma unroll
        for (int dt = 0; dt < 2; dt++) {
            float bb = bqkv[384 + 32 * w + 16 * dt + c16];
#pragma unroll
            for (int mt = 0; mt < 4; mt++) {
                f16x4 h;
#pragma unroll
                for (int r = 0; r < 4; r++) h[r] = (f16)(acc[dt][mt][r] + bb);
                *(f16x4*)(dstv + ((dt * 4 + mt) * 64 + l) * 4) = h;
            }
        }
    }
}

// =======================================================================
// SPLIT K23: attention + proj. 1 block = 1 window, 6 waves, wave=head.
// waves_per_eu(1,2); V + proj-weight + comb loads batch-hoisted.
// =======================================================================
__attribute__((amdgpu_waves_per_eu(1, 2)))
__global__ void __launch_bounds__(384)
attn2_kernel(const float* __restrict__ tau, const f16* __restrict__ Wpp,
             const float* __restrict__ bproj, const float* __restrict__ comb,
             const f16* __restrict__ qkv_ws, float* __restrict__ out) {
    __shared__ __align__(16) f16 ao[NT * STOK];

    const int tid = threadIdx.x;
    const int l   = tid & 63;
    const int w   = __builtin_amdgcn_readfirstlane(tid >> 6);
    const int b   = blockIdx.x;
    const int c16 = l & 15;
    const int g4  = l >> 4;

    const f16* qg = qkv_ws + (size_t)(b * NH + w) * 6144;
    const f16* kg = qg + 2048;
    const f16* vg = qg + 4096;

    // hoist: V PV-B-frags (8 loads) + proj weight frags (12 loads)
    f16x4 vb[2][4];
#pragma unroll
    for (int dt = 0; dt < 2; dt++)
#pragma unroll
        for (int mk = 0; mk < 4; mk++)
            vb[dt][mk] = *(const f16x4*)(vg + ((dt * 4 + mk) * 64 + l) * 4);
    f16x8 wpp[6][2];
#pragma unroll
    for (int ks = 0; ks < 6; ks++)
#pragma unroll
        for (int c2 = 0; c2 < 2; c2++)
            wpp[ks][c2] = *(const f16x8*)(Wpp + (((size_t)(2 * w + c2) * 6 + ks) * 64 + l) * 8);

    const float itau_l2 = LOG2E / fmaxf(tau[w], 0.01f);
    const float* cb = comb + ((size_t)((b & 63) * NH + w)) * (NT * NT);

    // attention in two nt-halves (keeps S-tile at 32 regs)
#pragma unroll
    for (int half = 0; half < 2; half++) {
        // hoist: comb vectors for this half (8 loads) before the MFMA chain
        f32x4 cc[4][2];
#pragma unroll
        for (int mt = 0; mt < 4; mt++)
#pragma unroll
            for (int ntl = 0; ntl < 2; ntl++)
                cc[mt][ntl] = *(const f32x4*)(cb + (16 * (2 * half + ntl) + c16) * NT + 16 * mt + 4 * g4);

        f16x8 aqf[2];
#pragma unroll
        for (int ntl = 0; ntl < 2; ntl++)
            aqf[ntl] = *(const f16x8*)(qg + (16 * (2 * half + ntl) + c16) * 32 + 8 * g4);
        f16x8 akf[4];
#pragma unroll
        for (int mt = 0; mt < 4; mt++)
            akf[mt] = *(const f16x8*)(kg + (16 * mt + c16) * 32 + 8 * g4);

        f32x4 sv[4][2];   // [mt][ntl]
#pragma unroll
        for (int mt = 0; mt < 4; mt++)
#pragma unroll
            for (int ntl = 0; ntl < 2; ntl++) {
                f32x4 z = {};
                sv[mt][ntl] = MFMA32(akf[mt], aqf[ntl], z);
            }
        // epilogue: scale + comb
#pragma unroll
        for (int mt = 0; mt < 4; mt++)
#pragma unroll
            for (int ntl = 0; ntl < 2; ntl++)
#pragma unroll
                for (int r = 0; r < 4; r++)
                    sv[mt][ntl][r] = sv[mt][ntl][r] * itau_l2 + cc[mt][ntl][r];
        // softmax over m, fold 1/sum
#pragma unroll
        for (int ntl = 0; ntl < 2; ntl++) {
            float mx = sv[0][ntl][0];
#pragma unroll
            for (int mt = 0; mt < 4; mt++)
#pragma unroll
                for (int r = 0; r < 4; r++) mx = fmaxf(mx, sv[mt][ntl][r]);
            mx = fmaxf(mx, __shfl_xor(mx, 16));
            mx = fmaxf(mx, __shfl_xor(mx, 32));
            float sum = 0.f;
#pragma unroll
            for (int mt = 0; mt < 4; mt++)
#pragma unroll
                for (int r = 0; r < 4; r++) {
                    float p = exp2f(sv[mt][ntl][r] - mx);
                    sv[mt][ntl][r] = p;
                    sum += p;
                }
            sum += __shfl_xor(sum, 16);
            sum += __shfl_xor(sum, 32);
            float ris = 1.0f / sum;
#pragma unroll
            for (int mt = 0; mt < 4; mt++)
#pragma unroll
                for (int r = 0; r < 4; r++) sv[mt][ntl][r] *= ris;
        }
        // P frags + PV
        f16x4 pa[4][2];
#pragma unroll
        for (int mk = 0; mk < 4; mk++)
#pragma unroll
            for (int ntl = 0; ntl < 2; ntl++) {
                f16x4 h;
#pragma unroll
                for (int r = 0; r < 4; r++) h[r] = (f16)sv[mk][ntl][r];
                pa[mk][ntl] = h;
            }
        f32x4 av[2][2] = {};
#pragma unroll
        for (int mk = 0; mk < 4; mk++)
#pragma unroll
            for (int ntl = 0; ntl < 2; ntl++)
#pragma unroll
                for (int dt = 0; dt < 2; dt++)
                    av[ntl][dt] = MFMA16(pa[mk][ntl], vb[dt][mk], av[ntl][dt]);
        // write ao LDS rows
#pragma unroll
        for (int ntl = 0; ntl < 2; ntl++)
#pragma unroll
            for (int dt = 0; dt < 2; dt++)
#pragma unroll
                for (int r = 0; r < 4; r++)
                    ao[(16 * (2 * half + ntl) + 4 * g4 + r) * STOK + 32 * w + 16 * dt + c16] =
                        (f16)av[ntl][dt][r];
    }
    __syncthreads();

    // proj GEMM (weights already in registers)
    f32x4 acc2[2][4] = {};
#pragma unroll
    for (int ks = 0; ks < 6; ks++) {
        f16x8 af[4];
#pragma unroll
        for (int rt = 0; rt < 4; rt++)
            af[rt] = *(const f16x8*)(ao + (16 * rt + c16) * STOK + ks * 32 + 8 * g4);
#pragma unroll
        for (int c2 = 0; c2 < 2; c2++)
#pragma unroll
            for (int rt = 0; rt < 4; rt++)
                acc2[c2][rt] = MFMA32(af[rt], wpp[ks][c2], acc2[c2][rt]);
    }
    float* ob = out + (size_t)b * (CH * NT);
#pragma unroll
    for (int c2 = 0; c2 < 2; c2++) {
        int c = 16 * (2 * w + c2) + c16;
        float bp = bproj[c];
#pragma unroll
        for (int rt = 0; rt < 4; rt++) {
            f32x4 o4 = acc2[c2][rt];
            o4[0] += bp; o4[1] += bp; o4[2] += bp; o4[3] += bp;
            *(f32x4*)(ob + c * NT + 16 * rt + 4 * g4) = o4;
        }
    }
}

// =======================================================================
// FUSED FALLBACK (r6 kernel, proven) — used when ws is too small
// =======================================================================
__launch_bounds__(384)
__global__ void attn_fused_kernel(const float* __restrict__ x, const float* __restrict__ bqkv,
                                  const float* __restrict__ bproj, const float* __restrict__ tau,
                                  const f16* __restrict__ Wpk, const f16* __restrict__ Wpp,
                                  const float* __restrict__ comb, float* __restrict__ out) {
    __shared__ __align__(16) char smem[SMEM_FUSED];
    f16* tok = (f16*)smem;
    f16* qk  = (f16*)smem;
    f16* ao  = (f16*)smem;

    const int b   = blockIdx.x;
    const int tid = threadIdx.x;
    const int l   = tid & 63;
    const int w   = __builtin_amdgcn_readfirstlane(tid >> 6);
    const int c16 = l & 15;
    const int g4  = l >> 4;

    {
        const float* xb = x + (size_t)b * (CH * NT);
        const int n4 = 4 * c16;
#pragma unroll
        for (int i = 0; i < 4; i++) {
            int c = 32 * w + 8 * g4 + 2 * i;
            f32x4 a0 = *(const f32x4*)(xb + c * NT + n4);
            f32x4 a1 = *(const f32x4*)(xb + (c + 1) * NT + n4);
#pragma unroll
            for (int j = 0; j < 4; j++) {
                f16x2 p;
                p[0] = (f16)a0[j];
                p[1] = (f16)a1[j];
                *(f16x2*)(tok + (n4 + j) * STOK + c) = p;
            }
        }
    }
    __syncthreads();

    f16x4 hq[2][4], hk[2][4];
    {
        f32x4 aq_[2][4] = {};
#pragma unroll
        for (int ks = 0; ks < 6; ks++) {
            f16x8 af[4];
#pragma unroll
            for (int nt = 0; nt < 4; nt++)
                af[nt] = *(const f16x8*)(tok + (16 * nt + c16) * STOK + ks * 32 + 8 * g4);
#pragma unroll
            for (int dt = 0; dt < 2; dt++) {
                f16x8 wf = *(const f16x8*)(Wpk + (((size_t)(2 * w + dt) * 6 + ks) * 64 + l) * 8);
#pragma unroll
                for (int nt = 0; nt < 4; nt++)
                    aq_[dt][nt] = MFMA32(wf, af[nt], aq_[dt][nt]);
            }
        }
#pragma unroll
        for (int dt = 0; dt < 2; dt++) {
            f32x4 bb = *(const f32x4*)(bqkv + 32 * w + 16 * dt + 4 * g4);
#pragma unroll
            for (int nt = 0; nt < 4; nt++)
#pragma unroll
                for (int r = 0; r < 4; r++) aq_[dt][nt][r] += bb[r];
        }
#pragma unroll
        for (int nt = 0; nt < 4; nt++) {
            float ss = 0.f;
#pragma unroll
            for (int dt = 0; dt < 2; dt++)
#pragma unroll
                for (int r = 0; r < 4; r++) ss += aq_[dt][nt][r] * aq_[dt][nt][r];
            ss += __shfl_xor(ss, 16);
            ss += __shfl_xor(ss, 32);
            float iq = 1.0f / fmaxf(sqrtf(ss), 1e-12f);
#pragma unroll
            for (int dt = 0; dt < 2; dt++)
#pragma unroll
                for (int r = 0; r < 4; r++) hq[dt][nt][r] = (f16)(aq_[dt][nt][r] * iq);
        }
    }
    {
        f32x4 ak_[2][4] = {};
#pragma unroll
        for (int ks = 0; ks < 6; ks++) {
            f16x8 af[4];
#pragma unroll
            for (int nt = 0; nt < 4; nt++)
                af[nt] = *(const f16x8*)(tok + (16 * nt + c16) * STOK + ks * 32 + 8 * g4);
#pragma unroll
            for (int dt = 0; dt < 2; dt++) {
                f16x8 wf = *(const f16x8*)(Wpk + (((size_t)(12 + 2 * w + dt) * 6 + ks) * 64 + l) * 8);
#pragma unroll
                for (int nt = 0; nt < 4; nt++)
                    ak_[dt][nt] = MFMA32(wf, af[nt], ak_[dt][nt]);
            }
        }
#pragma unroll
        for (int dt = 0; dt < 2; dt++) {
            f32x4 bb = *(const f32x4*)(bqkv + 192 + 32 * w + 16 * dt + 4 * g4);
#pragma unroll
            for (int nt = 0; nt < 4; nt++)
#pragma unroll
                for (int r = 0; r < 4; r++) ak_[dt][nt][r] += bb[r];
        }
#pragma unroll
        for (int nt = 0; nt < 4; nt++) {
            float ss = 0.f;
#pragma unroll
            for (int dt = 0; dt < 2; dt++)
#pragma unroll
                for (int r = 0; r < 4; r++) ss += ak_[dt][nt][r] * ak_[dt][nt][r];
            ss += __shfl_xor(ss, 16);
            ss += __shfl_xor(ss, 32);
            float ik = 1.0f / fmaxf(sqrtf(ss), 1e-12f);
#pragma unroll
            for (int dt = 0; dt < 2; dt++)
#pragma unroll
                for (int r = 0; r < 4; r++) hk[dt][nt][r] = (f16)(ak_[dt][nt][r] * ik);
        }
    }
    f16x4 vb[2][4];
    {
        f32x4 av_[2][4] = {};
#pragma unroll
        for (int ks = 0; ks < 6; ks++) {
            f16x8 af[4];
#pragma unroll
            for (int mt = 0; mt < 4; mt++)
                af[mt] = *(const f16x8*)(tok + (16 * mt + c16) * STOK + ks * 32 + 8 * g4);
#pragma unroll
            for (int dt = 0; dt < 2; dt++) {
                f16x8 wf = *(const f16x8*)(Wpk + (((size_t)(24 + 2 * w + dt) * 6 + ks) * 64 + l) * 8);
#pragma unroll
                for (int mt = 0; mt < 4; mt++)
                    av_[dt][mt] = MFMA32(af[mt], wf, av_[dt][mt]);
            }
        }
#pragma unroll
        for (int dt = 0; dt < 2; dt++) {
            float bb = bqkv[384 + 32 * w + 16 * dt + c16];
#pragma unroll
            for (int mt = 0; mt < 4; mt++)
#pragma unroll
                for (int r = 0; r < 4; r++) vb[dt][mt][r] = (f16)(av_[dt][mt][r] + bb);
        }
    }
    __syncthreads();

    f16* qh = qk + (w * 2 + 0) * 2048;
    f16* kh = qk + (w * 2 + 1) * 2048;
#pragma unroll
    for (int nt = 0; nt < 4; nt++)
#pragma unroll
        for (int dt = 0; dt < 2; dt++) {
            int base = qkidx(16 * nt + c16, 16 * dt + 4 * g4);
            *(f16x2*)(qh + base)     = f16x2{hq[dt][nt][0], hq[dt][nt][1]};
            *(f16x2*)(qh + base + 2) = f16x2{hq[dt][nt][2], hq[dt][nt][3]};
            *(f16x2*)(kh + base)     = f16x2{hk[dt][nt][0], hk[dt][nt][1]};
            *(f16x2*)(kh + base + 2) = f16x2{hk[dt][nt][2], hk[dt][nt][3]};
        }

    f32x4 sv[4][4];
    {
        f16x8 aqf[4];
#pragma unroll
        for (int t = 0; t < 4; t++)
            aqf[t] = *(const f16x8*)(qh + qkidx(16 * t + c16, 8 * g4));
#pragma unroll
        for (int mt = 0; mt < 4; mt++) {
            f16x8 akf = *(const f16x8*)(kh + qkidx(16 * mt + c16, 8 * g4));
#pragma unroll
            for (int nt = 0; nt < 4; nt++) {
                f32x4 z = {};
                sv[mt][nt] = MFMA32(akf, aqf[nt], z);
            }
        }
    }
    {
        const float itau_l2 = LOG2E / fmaxf(tau[w], 0.01f);
        const float* cb = comb + ((size_t)((b & 63) * NH + w)) * (NT * NT);
#pragma unroll
        for (int mt = 0; mt < 4; mt++)
#pragma unroll
            for (int nt = 0; nt < 4; nt++) {
                f32x4 cc = *(const f32x4*)(cb + (16 * nt + c16) * NT + 16 * mt + 4 * g4);
#pragma unroll
                for (int r = 0; r < 4; r++)
                    sv[mt][nt][r] = sv[mt][nt][r] * itau_l2 + cc[r];
            }
    }
#pragma unroll
    for (int nt = 0; nt < 4; nt++) {
        float mx = sv[0][nt][0];
#pragma unroll
        for (int mt = 0; mt < 4; mt++)
#pragma unroll
            for (int r = 0; r < 4; r++) mx = fmaxf(mx, sv[mt][nt][r]);
        mx = fmaxf(mx, __shfl_xor(mx, 16));
        mx = fmaxf(mx, __shfl_xor(mx, 32));
        float sum = 0.f;
#pragma unroll
        for (int mt = 0; mt < 4; mt++)
#pragma unroll
            for (int r = 0; r < 4; r++) {
                float p = exp2f(sv[mt][nt][r] - mx);
                sv[mt][nt][r] = p;
                sum += p;
            }
        sum += __shfl_xor(sum, 16);
        sum += __shfl_xor(sum, 32);
        float ris = 1.0f / sum;
#pragma unroll
        for (int mt = 0; mt < 4; mt++)
#pragma unroll
            for (int r = 0; r < 4; r++) sv[mt][nt][r] *= ris;
    }
    f16x4 pa[4][4];
#pragma unroll
    for (int mk = 0; mk < 4; mk++)
#pragma unroll
        for (int nt = 0; nt < 4; nt++) {
            f16x4 h;
#pragma unroll
            for (int r = 0; r < 4; r++) h[r] = (f16)sv[mk][nt][r];
            pa[mk][nt] = h;
        }
    f32x4 av[4][2] = {};
#pragma unroll
    for (int mk = 0; mk < 4; mk++)
#pragma unroll
        for (int nt = 0; nt < 4; nt++)
#pragma unroll
            for (int dt = 0; dt < 2; dt++)
                av[nt][dt] = MFMA16(pa[mk][nt], vb[dt][mk], av[nt][dt]);

    __syncthreads();
#pragma unroll
    for (int nt = 0; nt < 4; nt++)
#pragma unroll
        for (int dt = 0; dt < 2; dt++)
#pragma unroll
            for (int r = 0; r < 4; r++)
                ao[(16 * nt + 4 * g4 + r) * STOK + 32 * w + 16 * dt + c16] = (f16)av[nt][dt][r];
    __syncthreads();

    f32x4 acc2[2][4] = {};
#pragma unroll
    for (int ks = 0; ks < 6; ks++) {
        f16x8 af[4];
#pragma unroll
        for (int rt = 0; rt < 4; rt++)
            af[rt] = *(const f16x8*)(ao + (16 * rt + c16) * STOK + ks * 32 + 8 * g4);
#pragma unroll
        for (int c2 = 0; c2 < 2; c2++) {
            f16x8 bw = *(const f16x8*)(Wpp + (((size_t)(2 * w + c2) * 6 + ks) * 64 + l) * 8);
#pragma unroll
            for (int rt = 0; rt < 4; rt++)
                acc2[c2][rt] = MFMA32(af[rt], bw, acc2[c2][rt]);
        }
    }
    float* ob = out + (size_t)b * (CH * NT);
#pragma unroll
    for (int c2 = 0; c2 < 2; c2++) {
        int c = 16 * (2 * w + c2) + c16;
        float bp = bproj[c];
#pragma unroll
        for (int rt = 0; rt < 4; rt++) {
            f32x4 o4 = acc2[c2][rt];
            o4[0] += bp; o4[1] += bp; o4[2] += bp; o4[3] += bp;
            *(f32x4*)(ob + c * NT + 16 * rt + 4 * g4) = o4;
        }
    }
}

// ---------------- launcher ----------------
#define WS_BIAS 0
#define WS_WPK  98304
#define WS_WPP  319488
#define WS_COMB 393216
#define WS_QKV  6684672
#define WS_NEED ((size_t)WS_QKV + (size_t)BWIN * NH * 6144 * 2)

extern "C" void kernel_launch(void* const* d_in, const int* in_sizes, int n_in,
                              void* d_out, int out_size, void* d_ws, size_t ws_size,
                              hipStream_t stream) {
    const float* x     = (const float*)d_in[0];
    const float* mask  = (const float*)d_in[1];
    const float* Wqkv  = (const float*)d_in[2];
    const float* bqkv  = (const float*)d_in[3];
    const float* Wproj = (const float*)d_in[4];
    const float* bproj = (const float*)d_in[5];
    const float* mW1   = (const float*)d_in[6];
    const float* mb1   = (const float*)d_in[7];
    const float* mW2   = (const float*)d_in[8];
    const float* mb2   = (const float*)d_in[9];
    const float* tau   = (const float*)d_in[10];

    char* ws = (char*)d_ws;
    float* bias_tbl = (float*)(ws + WS_BIAS);
    f16*   Wpk      = (f16*)(ws + WS_WPK);
    f16*   Wpp      = (f16*)(ws + WS_WPP);
    float* comb     = (float*)(ws + WS_COMB);
    f16*   qkv_ws   = (f16*)(ws + WS_QKV);

    bias_kernel<<<16, 256, 0, stream>>>(mW1, mb1, mW2, mb2, bias_tbl);
    int prep_n = 36 * 6 * 64 * 8 + 12 * 6 * 64 * 8;
    prep_kernel<<<(prep_n + 255) / 256, 256, 0, stream>>>(Wqkv, Wproj, Wpk, Wpp);
    int comb_n = 64 * NH * NT * NT;
    comb_kernel<<<(comb_n + 255) / 256, 256, 0, stream>>>(mask, bias_tbl, comb);

    if (ws_size >= WS_NEED) {
        qkv_kernel<<<BWIN, 384, 0, stream>>>(x, bqkv, Wpk, qkv_ws);
        attn2_kernel<<<BWIN, 384, 0, stream>>>(tau, Wpp, bproj, comb, qkv_ws, (float*)d_out);
    } else {
        attn_fused_kernel<<<BWIN, 384, 0, stream>>>(x, bqkv, bproj, tau, Wpk, Wpp, comb,
                                                    (float*)d_out);
    }
}